// Round 11
// baseline (80.642 us; speedup 1.0000x reference)
//
#include <hip/hip_runtime.h>

typedef _Float16 half4v __attribute__((ext_vector_type(4)));
typedef __fp16 fp16x2 __attribute__((ext_vector_type(2)));
typedef float float4v __attribute__((ext_vector_type(4)));

#define S_ 1024
#define H_ 8
#define B_ 8
#define BH 64           // B*H
#define NROW 8192       // B*S
#define E_ 64

// Pack 4 floats -> half4v via v_cvt_pkrtz_f16_f32.
static __device__ inline half4v pack4(float a, float b, float c, float d) {
    union { fp16x2 f2[2]; half4v h4; } u;
    u.f2[0] = __builtin_amdgcn_cvt_pkrtz(a, b);
    u.f2[1] = __builtin_amdgcn_cvt_pkrtz(c, d);
    return u.h4;
}

// ---------------------------------------------------------------------------
// proj_kernel: closed-form quantum heads -> GLOBAL pre-swizzled fragments.
//   proj_w = prod_{i=0..w} cos(x_i+th_i) (w>=1); proj_0 = prod_{1..7}.
// kG[bh][kt*128 + g*64 + c*4 + j] = e_{g*4+j}(s=kt*16+c)   (K/Q A- and
//   B-operand fragment layout for mfma1, lanes 0..31; lanes 32..63 of the
//   consumer mirror via (lane&31) -> HW broadcast).
// vG[bh][kt*256 + lane*4 + j]: V'-frag for mfma2: lane=(quad<<4)|col holds
//   V'[key=kt*16+quad*4+j][col] where col 8 = ones (l-trick) and cols 9..15
//   mirror cols 1..7 (junk feeds O^T rows 9..15, never read).
// One thread per s; 256 blocks. Done ONCE per bh (was 16x redundant in LDS).
// ---------------------------------------------------------------------------
__global__ __launch_bounds__(256) void proj_kernel(
        const float* __restrict__ x, const float* __restrict__ theta,
        _Float16* __restrict__ kG, _Float16* __restrict__ vG) {
    int bh = blockIdx.x >> 2;
    int s  = ((blockIdx.x & 3) << 8) + threadIdx.x;
    int b = bh >> 3, h = bh & 7;

    const float4* xp = (const float4*)(x + (((size_t)(b << 10) + s) << 6) + (h << 3));
    float4 x0 = xp[0];
    float4 x1 = xp[1];
    float c0 = __cosf(x0.x + theta[0]);
    float c1 = __cosf(x0.y + theta[1]);
    float c2 = __cosf(x0.z + theta[2]);
    float c3 = __cosf(x0.w + theta[3]);
    float c4 = __cosf(x1.x + theta[4]);
    float c5 = __cosf(x1.y + theta[5]);
    float c6 = __cosf(x1.z + theta[6]);
    float c7 = __cosf(x1.w + theta[7]);
    float e1 = c0 * c1;
    float e2 = e1 * c2;
    float e3 = e2 * c3;
    float e4 = e3 * c4;
    float e5 = e4 * c5;
    float e6 = e5 * c6;
    float e7 = e6 * c7;
    float e0 = ((c1 * c2) * (c3 * c4)) * ((c5 * c6) * c7);
    half4v lo = pack4(e0, e1, e2, e3);
    half4v hi = pack4(e4, e5, e6, e7);

    int kt = s >> 4, c = s & 15;
    _Float16* kgb = kG + (size_t)bh * 8192;
    _Float16* vgb = vG + (size_t)bh * 16384;
    *(half4v*)&kgb[kt * 128 + c * 4]      = lo;
    *(half4v*)&kgb[kt * 128 + 64 + c * 4] = hi;

    // vG scatter: this thread's key position is (quad = c>>2, j = c&3).
    _Float16 arr[9] = {lo[0], lo[1], lo[2], lo[3], hi[0], hi[1], hi[2], hi[3],
                       (_Float16)1.0f};
    int quad = c >> 2, j = c & 3;
    int base = kt * 256 + (quad << 6) + j;
#pragma unroll
    for (int col = 0; col < 16; ++col) {
        vgb[base + col * 4] = arr[(col < 9) ? col : (col - 8)];
    }
}

// ---------------------------------------------------------------------------
// attn_kernel: MFMA flash attention per (b,h), O^T formulation. NO LDS, NO
// syncthreads: all fragments stream from L2-resident kG/vG (64 KB per bh,
// reused by 16 blocks). Per kt: one 256 B/wave coalesced K-frag load
// (lanes 32..63 broadcast via lane&31; garbage A[k>=8] nullified by qf=0
// at quads>=2) and one 512 B/wave V-frag load. Global loads pipeline to
// vmcnt depth across the unrolled loop (LDS lgkmcnt serialization gone).
// J=4 independent key-quarter chains per wave (R10 structure).
// mfma1: A=K-frag, B=Q-frag -> S^T == B-layout of P. P = exp2(S), no shift
// (uniform scaling cancels in o/l; |S|log2e <= 4.081).
// mfma2: A=V'-frag, B=P -> O^T; ones col gives l at lane 32|q, reg 0.
// Grid (64,16) = 1024 blocks = 4 blocks/CU.
// ---------------------------------------------------------------------------
__global__ __launch_bounds__(256, 4) void attn_kernel(
        const _Float16* __restrict__ kG, const _Float16* __restrict__ vG,
        _Float16* __restrict__ attnH) {
    int bh = blockIdx.x;
    int b = bh >> 3, h = bh & 7;
    int tid = threadIdx.x;
    int lane = tid & 63;
    int wv   = tid >> 6;
    int col  = lane & 15;
    int quad = lane >> 4;
    int q0   = blockIdx.y * 64 + wv * 16;
    bool lo2 = (quad < 2);

    const _Float16* kgb = kG + (size_t)bh * 8192;
    const _Float16* vgb = vG + (size_t)bh * 16384;
    int kaddr = (lane & 31) * 4;
    int vaddr = lane * 4;

    // Q-frag (loop-invariant B of mfma1): quads>=2 ZERO -> kills K garbage
    half4v qf = {(_Float16)0.f, (_Float16)0.f, (_Float16)0.f, (_Float16)0.f};
    if (lo2) qf = *(const half4v*)&kgb[kaddr + (q0 >> 4) * 128];
    qf *= (_Float16)0.51012921f;            // log2(e)/sqrt(8)

    const float4v zc = {0.f, 0.f, 0.f, 0.f};
    float4v o0 = zc, o1 = zc, o2 = zc, o3 = zc;

#pragma unroll
    for (int kt = 0; kt < 16; ++kt) {
        half4v k0 = *(const half4v*)&kgb[kaddr + (kt +  0) * 128];
        half4v k1 = *(const half4v*)&kgb[kaddr + (kt + 16) * 128];
        half4v k2 = *(const half4v*)&kgb[kaddr + (kt + 32) * 128];
        half4v k3 = *(const half4v*)&kgb[kaddr + (kt + 48) * 128];
        half4v v0 = *(const half4v*)&vgb[vaddr + (kt +  0) * 256];
        half4v v1 = *(const half4v*)&vgb[vaddr + (kt + 16) * 256];
        half4v v2 = *(const half4v*)&vgb[vaddr + (kt + 32) * 256];
        half4v v3 = *(const half4v*)&vgb[vaddr + (kt + 48) * 256];
        float4v s0 = __builtin_amdgcn_mfma_f32_16x16x16f16(k0, qf, zc, 0, 0, 0);
        float4v s1 = __builtin_amdgcn_mfma_f32_16x16x16f16(k1, qf, zc, 0, 0, 0);
        float4v s2 = __builtin_amdgcn_mfma_f32_16x16x16f16(k2, qf, zc, 0, 0, 0);
        float4v s3 = __builtin_amdgcn_mfma_f32_16x16x16f16(k3, qf, zc, 0, 0, 0);
        half4v p0 = pack4(__builtin_amdgcn_exp2f(s0[0]), __builtin_amdgcn_exp2f(s0[1]),
                          __builtin_amdgcn_exp2f(s0[2]), __builtin_amdgcn_exp2f(s0[3]));
        half4v p1 = pack4(__builtin_amdgcn_exp2f(s1[0]), __builtin_amdgcn_exp2f(s1[1]),
                          __builtin_amdgcn_exp2f(s1[2]), __builtin_amdgcn_exp2f(s1[3]));
        half4v p2 = pack4(__builtin_amdgcn_exp2f(s2[0]), __builtin_amdgcn_exp2f(s2[1]),
                          __builtin_amdgcn_exp2f(s2[2]), __builtin_amdgcn_exp2f(s2[3]));
        half4v p3 = pack4(__builtin_amdgcn_exp2f(s3[0]), __builtin_amdgcn_exp2f(s3[1]),
                          __builtin_amdgcn_exp2f(s3[2]), __builtin_amdgcn_exp2f(s3[3]));
        o0 = __builtin_amdgcn_mfma_f32_16x16x16f16(v0, p0, o0, 0, 0, 0);
        o1 = __builtin_amdgcn_mfma_f32_16x16x16f16(v1, p1, o1, 0, 0, 0);
        o2 = __builtin_amdgcn_mfma_f32_16x16x16f16(v2, p2, o2, 0, 0, 0);
        o3 = __builtin_amdgcn_mfma_f32_16x16x16f16(v3, p3, o3, 0, 0, 0);
    }

    float4v oacc;
#pragma unroll
    for (int r = 0; r < 4; ++r) oacc[r] = (o0[r] + o1[r]) + (o2[r] + o3[r]);

    // l[q] = ones-col (row 8 of O^T): lane 32|q, reg 0.
    float l = __shfl(oacc[0], 32 | col, 64);
    if (lo2) {
        float inv = __builtin_amdgcn_rcpf(l);
        half4v ov = pack4(oacc[0] * inv, oacc[1] * inv, oacc[2] * inv, oacc[3] * inv);
        *(half4v*)(attnH + (((size_t)(b << 10) + q0 + col) << 6) + (h << 3) + quad * 4) = ov;
    }
}

// ---------------------------------------------------------------------------
// MFMA combine: out[r,e] = sum_k A[r,k] * W[e,k], A f16 [8192][64], W f32.
// Block = 64 rows, 4 waves. W-frags loop-invariant; 16 MFMAs per wave.
// ---------------------------------------------------------------------------
__global__ __launch_bounds__(256) void combine_kernel(
        const _Float16* __restrict__ AH, const float* __restrict__ W,
        float* __restrict__ out) {
    __shared__ _Float16 a2[64 * 68];
    __shared__ _Float16 wt[64 * 68];        // wt[k*68+e] = W[e][k]
    int r0 = blockIdx.x * 64;
    int tid = threadIdx.x;

    for (int idx = tid; idx < E_ * E_; idx += 256) {
        int e = idx >> 6, k = idx & 63;
        wt[k * 68 + e] = (_Float16)W[idx];
    }
#pragma unroll
    for (int j = 0; j < 4; ++j) {
        int off = tid * 16 + j * 4;         // 0..4095
        int row = off >> 6, k = off & 63;
        *(half4v*)&a2[row * 68 + k] = *(const half4v*)&AH[(size_t)r0 * E_ + off];
    }
    __syncthreads();

    int lane = tid & 63;
    int wv   = tid >> 6;
    int col  = lane & 15;
    int quad = lane >> 4;

    // W-frags: B[k=t*16+quad*4+j][n=e0*16+col]
    half4v wf[4][4];
#pragma unroll
    for (int t = 0; t < 4; ++t)
#pragma unroll
        for (int e = 0; e < 4; ++e) {
            int kb = (t * 16 + quad * 4) * 68 + e * 16 + col;
            half4v w_ = {wt[kb], wt[kb + 68], wt[kb + 136], wt[kb + 204]};
            wf[t][e] = w_;
        }

    float4v acc[4] = {{0,0,0,0},{0,0,0,0},{0,0,0,0},{0,0,0,0}};
#pragma unroll
    for (int t = 0; t < 4; ++t) {
        half4v af = *(const half4v*)&a2[(wv * 16 + col) * 68 + t * 16 + quad * 4];
#pragma unroll
        for (int e = 0; e < 4; ++e)
            acc[e] = __builtin_amdgcn_mfma_f32_16x16x16f16(af, wf[t][e], acc[e], 0, 0, 0);
    }

#pragma unroll
    for (int e = 0; e < 4; ++e)
#pragma unroll
        for (int r = 0; r < 4; ++r)
            out[(size_t)(r0 + wv * 16 + quad * 4 + r) * E_ + e * 16 + col] = acc[e][r];
}

// ---------------------------------------------------------------------------
extern "C" void kernel_launch(void* const* d_in, const int* in_sizes, int n_in,
                              void* d_out, int out_size, void* d_ws, size_t ws_size,
                              hipStream_t stream) {
    const float* x     = (const float*)d_in[0];   // [8,1024,64] fp32
    const float* theta = (const float*)d_in[1];   // [8]
    const float* W     = (const float*)d_in[2];   // [64,64]
    float* out = (float*)d_out;                   // [8,1024,64]

    _Float16* attnH = (_Float16*)d_ws;                          // 1 MB
    _Float16* kG    = (_Float16*)((char*)d_ws + (1 << 20));     // 1 MB
    _Float16* vG    = (_Float16*)((char*)d_ws + (2 << 20));     // 2 MB

    proj_kernel<<<BH * 4, 256, 0, stream>>>(x, theta, kG, vG);
    attn_kernel<<<dim3(BH, S_ / 64), 256, 0, stream>>>(kG, vG, attnH);
    combine_kernel<<<NROW / 64, 256, 0, stream>>>(attnH, W, out);
}